// Round 8
// baseline (608.756 us; speedup 1.0000x reference)
//
#include <hip/hip_runtime.h>
#include <stdint.h>

#define V_N 100000
#define E_N 50000
#define C_N 128

// counting-sort geometry: 256 keys per bucket
#define NB_E 196                 // ceil(50000/256)
#define NB_V 391                 // ceil(100000/256)
#define NBINS (NB_E + NB_V)      // 587
#define CHUNK 8192               // entries per pass-A/hist block
#define CAP_B 10240              // passB LDS value-staging capacity (mean 8192/4096, +20 sigma)
#define G1T 782                  // gemm1 tiles = ceil(V_N/128)
#define G2T 391                  // gemm2 tiles = ceil(E_N/128)

typedef unsigned short u16;
typedef unsigned int u32;
typedef float f32x4 __attribute__((ext_vector_type(4)));   // native vec for nontemporal builtins

// ---------- bf16 helpers ----------
__device__ __forceinline__ u16 f2bf(float f) {
    union { float f; u32 i; } c; c.f = f;
    u32 i = c.i;
    i += 0x7fffu + ((i >> 16) & 1u);   // RNE
    return (u16)(i >> 16);
}
__device__ __forceinline__ void unpack2(u32 u, float& lo, float& hi) {
    union { u32 i; float f; } a, b;
    a.i = u << 16; b.i = u & 0xffff0000u;
    lo = a.f; hi = b.f;
}

__global__ __launch_bounds__(64) void flagf_k(float* out, float v) {
    if (threadIdx.x == 0 && blockIdx.x == 0) out[0] = v;
}

__global__ __launch_bounds__(256) void zero_i4(int4* __restrict__ p, int n) {
    int i = blockIdx.x * 256 + threadIdx.x;
    if (i < n) { int4 z = {0, 0, 0, 0}; p[i] = z; }
}

// ---------- GEMM body (round-4 structure + T14 async-stage split) ----------
// MODE 0 (gemm1): A = X normal [M][128] f32; C -> Xp blocked [8][M][16] bf16; post=id
// MODE 1 (gemm2): A = Ysum blocked [8][M][16] f32 (already relu'd);
//                 C -> Yp blocked [4][M][32] bf16; post = *1/max(len,1)
template<int MODE>
__device__ __forceinline__ void gemm_body(float* As, float* Wsh, int tile,
                                          const float* __restrict__ A,
                                          const float* __restrict__ W,
                                          const float* __restrict__ bias,
                                          const int* __restrict__ off,
                                          u16* __restrict__ Cout, int M) {
    const int tid = threadIdx.x;
    const int tx = tid & 15;     // n-group
    const int ty = tid >> 4;     // m-group (0..15)
    const int m0 = tile * 128;

    float4 ra[4], rw[4];         // staging registers (A-slice, W-slice)

    auto loadSlice = [&](int kk) {
        #pragma unroll
        for (int u = 0; u < 4; ++u) {
            int f = tid + u * 256;
            int r = f >> 3, c4 = f & 7;
            float4 val = { 0.f, 0.f, 0.f, 0.f };
            int rg = m0 + r;
            if (rg < M) {
                if (MODE == 0) {
                    val = *(const float4*)(A + (size_t)rg * C_N + kk + c4 * 4);
                } else {
                    int sl = (kk >> 4) + (c4 >> 2);    // blocked-8 input
                    val = *(const float4*)(A + ((size_t)sl * M + rg) * 16 + (c4 & 3) * 4);
                }
            }
            ra[u] = val;
            int rwr = f >> 5, cw = f & 31;
            rw[u] = *(const float4*)(W + (size_t)(kk + rwr) * C_N + cw * 4);
        }
    };
    auto writeSlice = [&]() {
        #pragma unroll
        for (int u = 0; u < 4; ++u) {
            int f = tid + u * 256;
            int r = f >> 3, c4 = f & 7;
            int sc4 = c4 ^ ((r >> 3) & 7);
            *(float4*)(As + r * 32 + sc4 * 4) = ra[u];
            int rwr = f >> 5, cw = f & 31;
            *(float4*)(Wsh + rwr * 128 + cw * 4) = rw[u];
        }
    };

    float acc[8][8];
    #pragma unroll
    for (int i = 0; i < 8; ++i)
        #pragma unroll
        for (int j = 0; j < 8; ++j) acc[i][j] = 0.f;

    loadSlice(0);
    writeSlice();
    __syncthreads();

    #pragma unroll 1
    for (int kk = 0; kk < 128; kk += 32) {
        if (kk < 96) loadSlice(kk + 32);        // issue next-slice loads (regs)
        #pragma unroll
        for (int k4 = 0; k4 < 32; k4 += 4) {
            float4 a[8];
            #pragma unroll
            for (int i = 0; i < 8; ++i) {
                int row = ty * 8 + i;           // row>>3 == ty
                int sc4 = (k4 >> 2) ^ (ty & 7);
                a[i] = *(const float4*)(As + row * 32 + sc4 * 4);
            }
            #pragma unroll
            for (int dk = 0; dk < 4; ++dk) {
                float4 w0 = *(const float4*)(Wsh + (k4 + dk) * 128 + tx * 4);
                float4 w1 = *(const float4*)(Wsh + (k4 + dk) * 128 + 64 + tx * 4);
                #pragma unroll
                for (int i = 0; i < 8; ++i) {
                    float av = (dk == 0) ? a[i].x : (dk == 1) ? a[i].y : (dk == 2) ? a[i].z : a[i].w;
                    acc[i][0] = fmaf(av, w0.x, acc[i][0]);
                    acc[i][1] = fmaf(av, w0.y, acc[i][1]);
                    acc[i][2] = fmaf(av, w0.z, acc[i][2]);
                    acc[i][3] = fmaf(av, w0.w, acc[i][3]);
                    acc[i][4] = fmaf(av, w1.x, acc[i][4]);
                    acc[i][5] = fmaf(av, w1.y, acc[i][5]);
                    acc[i][6] = fmaf(av, w1.z, acc[i][6]);
                    acc[i][7] = fmaf(av, w1.w, acc[i][7]);
                }
            }
        }
        if (kk < 96) {
            __syncthreads();    // everyone done reading As/Wsh
            writeSlice();       // vmcnt wait lands here, after compute
            __syncthreads();    // slice ready
        }
    }

    float4 bb0 = *(const float4*)(bias + tx * 4);
    float4 bb1 = *(const float4*)(bias + 64 + tx * 4);
    #pragma unroll
    for (int i = 0; i < 8; ++i) {
        int m = m0 + ty * 8 + i;
        if (m >= M) break;
        float inv = 1.f;
        if (MODE) { int len = off[m + 1] - off[m]; inv = 1.f / (float)max(len, 1); }
        float v0, v1, v2, v3, v4, v5, v6, v7;
        if (MODE) {
            v0 = acc[i][0] * inv + bb0.x; v1 = acc[i][1] * inv + bb0.y;
            v2 = acc[i][2] * inv + bb0.z; v3 = acc[i][3] * inv + bb0.w;
            v4 = acc[i][4] * inv + bb1.x; v5 = acc[i][5] * inv + bb1.y;
            v6 = acc[i][6] * inv + bb1.z; v7 = acc[i][7] * inv + bb1.w;
        } else {
            v0 = acc[i][0] + bb0.x; v1 = acc[i][1] + bb0.y;
            v2 = acc[i][2] + bb0.z; v3 = acc[i][3] + bb0.w;
            v4 = acc[i][4] + bb1.x; v5 = acc[i][5] + bb1.y;
            v6 = acc[i][6] + bb1.z; v7 = acc[i][7] + bb1.w;
        }
        u32 p0 = (u32)f2bf(v0) | ((u32)f2bf(v1) << 16);
        u32 p1 = (u32)f2bf(v2) | ((u32)f2bf(v3) << 16);
        u32 p2 = (u32)f2bf(v4) | ((u32)f2bf(v5) << 16);
        u32 p3 = (u32)f2bf(v6) | ((u32)f2bf(v7) << 16);
        uint2 q0 = { p0, p1 }, q1 = { p2, p3 };
        if (MODE == 0) {
            // blocked-8 bf16 [8][M][16]: q0 ch 4tx.. -> slice tx>>2; q1 ch 64+4tx -> slice 4+(tx>>2)
            u32* d0 = (u32*)Cout + ((size_t)(tx >> 2) * M + m) * 8 + (tx & 3) * 2;
            u32* d1 = (u32*)Cout + ((size_t)(4 + (tx >> 2)) * M + m) * 8 + (tx & 3) * 2;
            *(uint2*)d0 = q0;
            *(uint2*)d1 = q1;
        } else {
            // blocked-4 bf16 [4][M][32]: q0 -> slice tx>>3; q1 -> slice 2+(tx>>3)
            u32* d0 = (u32*)Cout + ((size_t)(tx >> 3) * M + m) * 16 + (tx & 7) * 2;
            u32* d1 = (u32*)Cout + ((size_t)(2 + (tx >> 3)) * M + m) * 16 + (tx & 7) * 2;
            *(uint2*)d0 = q0;
            *(uint2*)d1 = q1;
        }
    }
}

// ---------- fused: blocks [0,G1T) = gemm1 tiles; blocks [G1T, G1T+NCH) = histogram ----------
__global__ __launch_bounds__(256) void g1hist_k(const float* __restrict__ X,
                                                const float* __restrict__ W,
                                                const float* __restrict__ bias,
                                                u16* __restrict__ Xp,
                                                const int* __restrict__ v_ids,
                                                const int* __restrict__ e_ids,
                                                int* __restrict__ gbin, int nnz) {
    __shared__ __align__(16) float sm[2][4096];   // 32KB: As | Wsh
    if ((int)blockIdx.x < G1T) {
        gemm_body<0>(sm[0], sm[1], blockIdx.x, X, W, bias, nullptr, Xp, V_N);
    } else {
        int* hb = (int*)sm;
        const int bid = blockIdx.x - G1T;
        for (int i = threadIdx.x; i < NBINS; i += 256) hb[i] = 0;
        __syncthreads();
        const int nnz4 = nnz >> 2;
        const int b4 = bid * (CHUNK >> 2);
        #pragma unroll
        for (int u = 0; u < 8; ++u) {
            int i4 = b4 + u * 256 + threadIdx.x;
            if (i4 < nnz4) {
                int4 e = ((const int4*)e_ids)[i4];
                int4 v = ((const int4*)v_ids)[i4];
                #define HA(ee, vv) \
                    if ((unsigned)ee < (unsigned)E_N && (unsigned)vv < (unsigned)V_N) { \
                        atomicAdd(&hb[ee >> 8], 1); atomicAdd(&hb[NB_E + (vv >> 8)], 1); }
                HA(e.x, v.x); HA(e.y, v.y); HA(e.z, v.z); HA(e.w, v.w);
                #undef HA
            }
        }
        __syncthreads();
        for (int i = threadIdx.x; i < NBINS; i += 256)
            if (hb[i]) atomicAdd(&gbin[i], hb[i]);
    }
}

__global__ __launch_bounds__(256) void gemm2_k(const float* __restrict__ A,
                                               const float* __restrict__ W,
                                               const float* __restrict__ bias,
                                               const int* __restrict__ off,
                                               u16* __restrict__ Cout, int M) {
    __shared__ __align__(16) float sm[2][4096];   // 32KB
    gemm_body<1>(sm[0], sm[1], blockIdx.x, A, W, bias, off, Cout, M);
}

// ---------- scanB: exclusive scan over bucket totals -> bases + cursors + off[N] ----------
__global__ __launch_bounds__(1024) void scanB_k(const int* __restrict__ gbin,
                                                int* __restrict__ base_e, int* __restrict__ base_v,
                                                int* __restrict__ curb_e, int* __restrict__ curb_v,
                                                int* __restrict__ off_e, int* __restrict__ off_v) {
    __shared__ int wtot[16];
    const int t = threadIdx.x, lane = t & 63, wid = t >> 6;
    // ---- e buckets ----
    {
        int x = (t < NB_E) ? gbin[t] : 0;
        int incl = x;
        for (int d = 1; d < 64; d <<= 1) { int u = __shfl_up(incl, d); if (lane >= d) incl += u; }
        if (lane == 63) wtot[wid] = incl;
        __syncthreads();
        int carry = 0;
        for (int w = 0; w < wid; ++w) carry += wtot[w];
        int excl = carry + incl - x;
        if (t < NB_E) { base_e[t] = excl; curb_e[t] = excl; }
        if (t == 0) {
            int tot = 0;
            for (int w = 0; w < 16; ++w) tot += wtot[w];
            base_e[NB_E] = tot; off_e[E_N] = tot;
        }
        __syncthreads();
    }
    // ---- v buckets ----
    {
        int x = (t < NB_V) ? gbin[NB_E + t] : 0;
        int incl = x;
        for (int d = 1; d < 64; d <<= 1) { int u = __shfl_up(incl, d); if (lane >= d) incl += u; }
        if (lane == 63) wtot[wid] = incl;
        __syncthreads();
        int carry = 0;
        for (int w = 0; w < wid; ++w) carry += wtot[w];
        int excl = carry + incl - x;
        if (t < NB_V) { base_v[t] = excl; curb_v[t] = excl; }
        if (t == 0) {
            int tot = 0;
            for (int w = 0; w < 16; ++w) tot += wtot[w];
            base_v[NB_V] = tot; off_v[V_N] = tot;
        }
    }
}

// ---------- passA: partition pairs into bucket-contiguous arrays (ids LDS-staged once) ----------
// pair pack: e-dir (elow 8b << 17) | v (17b);  v-dir (vlow 8b << 16) | e (16b)
__global__ __launch_bounds__(512) void passA_k(const int* __restrict__ v_ids,
                                               const int* __restrict__ e_ids,
                                               int* __restrict__ curb_e, int* __restrict__ curb_v,
                                               u32* __restrict__ pairs_e, u32* __restrict__ pairs_v,
                                               int nnz) {
    __shared__ __align__(16) int ids_e[CHUNK];
    __shared__ __align__(16) int ids_v[CHUNK];
    __shared__ __align__(16) u32 stage[CHUNK];
    __shared__ int cnt[512], runoff[513], delta[512], cnt2[512];
    __shared__ int wtot[8];
    const int t = threadIdx.x, lane = t & 63, wid = t >> 6;
    const int nnz4 = nnz >> 2;
    const int b4 = blockIdx.x * (CHUNK >> 2);

    // stage ids to LDS (single global read pass); invalid filler -1
    #pragma unroll
    for (int u = 0; u < 4; ++u) {
        int k4 = u * 512 + t;
        int i4 = b4 + k4;
        int4 e = { -1, -1, -1, -1 }, v = { -1, -1, -1, -1 };
        if (i4 < nnz4) { e = ((const int4*)e_ids)[i4]; v = ((const int4*)v_ids)[i4]; }
        ((int4*)ids_e)[k4] = e;
        ((int4*)ids_v)[k4] = v;
    }
    __syncthreads();

    for (int dir = 0; dir < 2; ++dir) {
        const int nb = dir ? NB_V : NB_E;
        cnt[t] = 0; cnt2[t] = 0;
        __syncthreads();
        // count
        for (int k = t; k < CHUNK; k += 512) {
            int ee = ids_e[k], vv = ids_v[k];
            if ((unsigned)ee < (unsigned)E_N && (unsigned)vv < (unsigned)V_N) {
                int key = dir ? vv : ee;
                atomicAdd(&cnt[key >> 8], 1);
            }
        }
        __syncthreads();
        // exclusive scan cnt[0..nb)
        int x = (t < nb) ? cnt[t] : 0;
        int incl = x;
        for (int d = 1; d < 64; d <<= 1) { int u = __shfl_up(incl, d); if (lane >= d) incl += u; }
        if (lane == 63) wtot[wid] = incl;
        __syncthreads();
        int carry = 0;
        for (int w = 0; w < wid; ++w) carry += wtot[w];
        int excl = carry + incl - x;
        if (t < nb) runoff[t] = excl;
        if (t == 0) {
            int tot = 0;
            for (int w = 0; w < 8; ++w) tot += wtot[w];
            runoff[nb] = tot;
        }
        __syncthreads();
        const int total = runoff[nb];
        // reserve global runs (one atomic per nonempty bucket)
        if (t < nb && cnt[t] > 0) {
            int r = atomicAdd((dir ? curb_v : curb_e) + t, cnt[t]);
            delta[t] = r - runoff[t];
        }
        __syncthreads();
        // scatter into LDS staging grouped by bucket
        for (int k = t; k < CHUNK; k += 512) {
            int ee = ids_e[k], vv = ids_v[k];
            if ((unsigned)ee < (unsigned)E_N && (unsigned)vv < (unsigned)V_N) {
                int key = dir ? vv : ee;
                int b_ = key >> 8;
                u32 pk_ = dir ? (((u32)(key & 255) << 16) | (u32)ee)
                              : (((u32)(key & 255) << 17) | (u32)vv);
                int idx_ = runoff[b_] + atomicAdd(&cnt2[b_], 1);
                stage[idx_] = pk_;
            }
        }
        __syncthreads();
        // coalesced flush (binary-search bucket of each staged slot)
        u32* pairs = dir ? pairs_v : pairs_e;
        for (int i = t; i < total; i += 512) {
            int lo = 0, hi = nb;
            while (hi - lo > 1) { int mid = (lo + hi) >> 1; if (runoff[mid] <= i) lo = mid; else hi = mid; }
            pairs[i + delta[lo]] = stage[i];
        }
        __syncthreads();
    }
}

// ---------- passB: per-bucket CSR finalize, LDS-staged, coalesced in/out ----------
__global__ __launch_bounds__(256) void passB_k(const u32* __restrict__ pairs_e,
                                               const u32* __restrict__ pairs_v,
                                               const int* __restrict__ base_e,
                                               const int* __restrict__ base_v,
                                               int* __restrict__ off_e, int* __restrict__ off_v,
                                               int* __restrict__ se_src, int* __restrict__ sv_src) {
    __shared__ int cntk[256], curk[256];
    __shared__ u32 buf[CAP_B];
    __shared__ int wtot[4];
    int b = blockIdx.x;
    const u32* pairs; const int* base; int* off; int* outv; int keyN, shift; u32 mask;
    if (b < NB_E) { pairs = pairs_e; base = base_e; off = off_e; outv = se_src; keyN = E_N; shift = 17; mask = 0x1FFFFu; }
    else { b -= NB_E; pairs = pairs_v; base = base_v; off = off_v; outv = sv_src; keyN = V_N; shift = 16; mask = 0xFFFFu; }
    const int lo = base[b], hi = base[b + 1], cnt = hi - lo, k0 = b << 8;
    const int t = threadIdx.x, lane = t & 63, wid = t >> 6;
    cntk[t] = 0;
    __syncthreads();
    for (int i = t; i < cnt; i += 256) { u32 p = pairs[lo + i]; atomicAdd(&cntk[p >> shift], 1); }
    __syncthreads();
    int x = cntk[t];
    int incl = x;
    for (int d = 1; d < 64; d <<= 1) { int u = __shfl_up(incl, d); if (lane >= d) incl += u; }
    if (lane == 63) wtot[wid] = incl;
    __syncthreads();
    int carry = 0;
    for (int w = 0; w < wid; ++w) carry += wtot[w];
    int excl = carry + incl - x;
    if (k0 + t < keyN) off[k0 + t] = lo + excl;
    curk[t] = excl;
    __syncthreads();
    if (cnt <= CAP_B) {
        for (int i = t; i < cnt; i += 256) {
            u32 p = pairs[lo + i];
            int pos = atomicAdd(&curk[p >> shift], 1);
            buf[pos] = p & mask;
        }
        __syncthreads();
        for (int i = t; i < cnt; i += 256) outv[lo + i] = (int)buf[i];
    } else {
        // statistically unreachable fallback (keeps correctness unconditional)
        for (int i = t; i < cnt; i += 256) {
            u32 p = pairs[lo + i];
            int pos = atomicAdd(&curk[p >> shift], 1);
            outv[lo + pos] = (int)(p & mask);
        }
    }
}

// ---------- segX: channel-sliced, XCD-pinned segment aggregation ----------
// MODE 0 (seg_e): table Xp blocked [8][V_N][16] bf16; N=E_N segs; out = YsumB
//                 blocked [8][E_N][16] f32 = relu(sum)  (/len folded into gemm2)
// MODE 1 (seg_v): table Yp blocked [4][E_N][32] bf16; N=V_N segs; out = normal
//                 [V_N][128] f32 = relu(sum/max(len,1))
// slice = blockIdx % NS rides the round-robin blockIdx->XCD mapping: each XCD
// gathers from ONE 3.2MB table slice that fits its private L2. Streams (srcs,
// output) are nontemporal so they can't evict the slice. 4 segs per wave give
// 4 independent gather chains.
template<int MODE>
__global__ __launch_bounds__(256) void segX_k(const u16* __restrict__ T,
                                              const int* __restrict__ off,
                                              const int* __restrict__ srcs,
                                              float* __restrict__ out,
                                              int N, int NSRC) {
    constexpr int NS    = MODE ? 4 : 8;    // channel slices
    constexpr int SCH   = MODE ? 32 : 16;  // channels per slice
    constexpr int BATCH = MODE ? 16 : 32;  // rows per load batch
    constexpr int RSH   = MODE ? 2 : 1;
    constexpr int HMSK  = MODE ? 3 : 1;
    constexpr int BSH   = MODE ? 2 : 3;    // log2(NS)
    const int slice = blockIdx.x & (NS - 1);
    const int wseg0 = ((blockIdx.x >> BSH) * 4 + (threadIdx.x >> 6)) * 4;
    const int lane = threadIdx.x & 63;
    const int r = lane >> RSH;             // row within batch
    const int h = lane & HMSK;             // 16B (8ch) chunk within row-slice
    const u16* Ts = T + (size_t)slice * NSRC * SCH;

    float acc[4][8];
    #pragma unroll
    for (int k = 0; k < 4; ++k)
        #pragma unroll
        for (int c = 0; c < 8; ++c) acc[k][c] = 0.f;

    int jc[4], j1[4], len[4];
    #pragma unroll
    for (int k = 0; k < 4; ++k) {
        int s = wseg0 + k;
        jc[k] = (s < N) ? off[s] : 0;
        j1[k] = (s < N) ? off[s + 1] : 0;
        len[k] = j1[k] - jc[k];
    }

    int rem = 1;
    while (rem) {
        rem = 0;
        int idx[4], ok[4];
        #pragma unroll
        for (int k = 0; k < 4; ++k) {
            ok[k] = (jc[k] + r < j1[k]);
            idx[k] = ok[k] ? __builtin_nontemporal_load(srcs + jc[k] + r) : 0;
        }
        #pragma unroll
        for (int k = 0; k < 4; ++k) {
            if (ok[k]) {
                uint4 q = *(const uint4*)(Ts + (size_t)idx[k] * SCH + h * 8);
                float l_, h_;
                unpack2(q.x, l_, h_); acc[k][0] += l_; acc[k][1] += h_;
                unpack2(q.y, l_, h_); acc[k][2] += l_; acc[k][3] += h_;
                unpack2(q.z, l_, h_); acc[k][4] += l_; acc[k][5] += h_;
                unpack2(q.w, l_, h_); acc[k][6] += l_; acc[k][7] += h_;
            }
        }
        #pragma unroll
        for (int k = 0; k < 4; ++k) { jc[k] += BATCH; rem |= (jc[k] < j1[k]) ? 1 : 0; }
    }

    // reduce over rows (lanes sharing h)
    #pragma unroll
    for (int k = 0; k < 4; ++k)
        #pragma unroll
        for (int c = 0; c < 8; ++c) {
            if (MODE == 0) acc[k][c] += __shfl_xor(acc[k][c], 2);
            acc[k][c] += __shfl_xor(acc[k][c], 4);
            acc[k][c] += __shfl_xor(acc[k][c], 8);
            acc[k][c] += __shfl_xor(acc[k][c], 16);
            acc[k][c] += __shfl_xor(acc[k][c], 32);
        }

    if (r == 0) {
        #pragma unroll
        for (int k = 0; k < 4; ++k) {
            int s = wseg0 + k;
            if (s < N) {
                float inv = MODE ? (1.0f / (float)max(len[k], 1)) : 1.0f;
                f32x4 w0, w1;
                w0.x = fmaxf(acc[k][0] * inv, 0.f); w0.y = fmaxf(acc[k][1] * inv, 0.f);
                w0.z = fmaxf(acc[k][2] * inv, 0.f); w0.w = fmaxf(acc[k][3] * inv, 0.f);
                w1.x = fmaxf(acc[k][4] * inv, 0.f); w1.y = fmaxf(acc[k][5] * inv, 0.f);
                w1.z = fmaxf(acc[k][6] * inv, 0.f); w1.w = fmaxf(acc[k][7] * inv, 0.f);
                float* o;
                if (MODE) o = out + (size_t)s * C_N + slice * SCH + h * 8;
                else      o = out + ((size_t)slice * N + s) * SCH + h * 8;
                __builtin_nontemporal_store(w0, (f32x4*)o);
                __builtin_nontemporal_store(w1, (f32x4*)o + 1);
            }
        }
    }
}

// ---------- launch ----------
extern "C" void kernel_launch(void* const* d_in, const int* in_sizes, int n_in,
                              void* d_out, int out_size, void* d_ws, size_t ws_size,
                              hipStream_t stream) {
    const float* X     = (const float*)d_in[0];
    const float* W_v2e = (const float*)d_in[1];
    const float* b_v2e = (const float*)d_in[2];
    const float* W_e2v = (const float*)d_in[3];
    const float* b_e2v = (const float*)d_in[4];
    const int*   v_ids = (const int*)d_in[5];
    const int*   e_ids = (const int*)d_in[6];
    float* out = (float*)d_out;   // f32 [V][128]

    bool sizesOK = (n_in == 7) && (out_size == 12800000)
        && in_sizes[0] == 12800000 && in_sizes[1] == 16384 && in_sizes[2] == 128
        && in_sizes[3] == 16384 && in_sizes[4] == 128
        && in_sizes[5] == 1600000 && in_sizes[6] == 1600000;
    if (!sizesOK) { flagf_k<<<1, 64, 0, stream>>>(out, 1.0e6f); return; }
    if (ws_size < 28000000) { flagf_k<<<1, 64, 0, stream>>>(out, 2.0e6f); return; }
    const int nnz = in_sizes[5];

    // d_out (51.2 MB) doubles as scratch:
    //   Xp blocked bf16 [8][V][16] @ 0 (25.6M)     -- written by g1hist, gathered by seg_e
    //   pairs_e u32[nnz] @ 25.6M, pairs_v @ 32M    -- written by passA, dead after passB
    //   YsumB blocked f32 [8][E][16] @ 25.6M       -- written by seg_e (over dead pairs)
    //   out f32 [V][128] @ 0                       -- final write by seg_v
    u16*   Xp      = (u16*)d_out;
    u32*   pairs_e = (u32*)((char*)d_out + 25600000);
    u32*   pairs_v = pairs_e + nnz;
    float* YsumB   = (float*)((char*)d_out + 25600000);

    // ws layout (bytes):
    char* ws = (char*)d_ws;
    u16* YpB    = (u16*)(ws + 0);                   // blocked bf16 [4][E][32] (12.8M)
    int* se_src = (int*)(ws + 12800000);            // int[nnz]
    int* sv_src = (int*)(ws + 19200000);            // int[nnz]
    int* gbin   = (int*)(ws + 25600000);            // 587 (+pad to 640)
    int* base_e = (int*)(ws + 25602560);            // 197
    int* base_v = (int*)(ws + 25603584);            // 392
    int* curb_e = (int*)(ws + 25605632);            // 196
    int* curb_v = (int*)(ws + 25606656);            // 391
    int* off_e  = (int*)(ws + 25608704);            // 50001
    int* off_v  = (int*)(ws + 25808768);            // 100001  (ends ~26.2M)

    const int NCH = (nnz + CHUNK - 1) / CHUNK;      // 196

    zero_i4<<<1, 256, 0, stream>>>((int4*)gbin, 152);   // 608 ints >= 587, within pad
    // gemm1 (782 tiles) + histogram (196 chunks, fills the drain tail)
    g1hist_k<<<G1T + NCH, 256, 0, stream>>>(X, W_v2e, b_v2e, Xp, v_ids, e_ids, gbin, nnz);
    scanB_k<<<1, 1024, 0, stream>>>(gbin, base_e, base_v, curb_e, curb_v, off_e, off_v);
    passA_k<<<NCH, 512, 0, stream>>>(v_ids, e_ids, curb_e, curb_v, pairs_e, pairs_v, nnz);
    passB_k<<<NBINS, 256, 0, stream>>>(pairs_e, pairs_v, base_e, base_v, off_e, off_v, se_src, sv_src);

    // seg_e: 3125 seg-groups x 8 slices; seg_v: 6250 seg-groups x 4 slices
    segX_k<0><<<((E_N + 15) / 16) * 8, 256, 0, stream>>>(Xp, off_e, se_src, YsumB, E_N, V_N);
    gemm2_k<<<G2T, 256, 0, stream>>>(YsumB, W_e2v, b_e2v, off_e, YpB, E_N);
    segX_k<1><<<((V_N + 15) / 16) * 4, 256, 0, stream>>>(YpB, off_v, sv_src, out, V_N, E_N);

    (void)ws_size;
}

// Round 9
// 376.921 us; speedup vs baseline: 1.6151x; 1.6151x over previous
//
#include <hip/hip_runtime.h>
#include <stdint.h>

#define V_N 100000
#define E_N 50000
#define C_N 128

// counting-sort geometry: 256 keys per bucket
#define NB_E 196                 // ceil(50000/256)
#define NB_V 391                 // ceil(100000/256)
#define NBINS (NB_E + NB_V)      // 587
#define CHUNK_H 8192             // entries per hist block
#define CHUNK_A 4096             // entries per passA block (LDS fits in 32KB union)
#define CAP_B 10240              // passB LDS value-staging capacity (mean 8192/4096, +20 sigma)
#define G1T 782                  // gemm1 tiles = ceil(V_N/128)
#define G2T 391                  // gemm2 tiles = ceil(E_N/128)

typedef unsigned short u16;
typedef unsigned int u32;

// ---------- bf16 helpers ----------
__device__ __forceinline__ u16 f2bf(float f) {
    union { float f; u32 i; } c; c.f = f;
    u32 i = c.i;
    i += 0x7fffu + ((i >> 16) & 1u);   // RNE
    return (u16)(i >> 16);
}
__device__ __forceinline__ void unpack2(u32 u, float& lo, float& hi) {
    union { u32 i; float f; } a, b;
    a.i = u << 16; b.i = u & 0xffff0000u;
    lo = a.f; hi = b.f;
}

__global__ __launch_bounds__(64) void flagf_k(float* out, float v) {
    if (threadIdx.x == 0 && blockIdx.x == 0) out[0] = v;
}

__global__ __launch_bounds__(256) void zero_i4(int4* __restrict__ p, int n) {
    int i = blockIdx.x * 256 + threadIdx.x;
    if (i < n) { int4 z = {0, 0, 0, 0}; p[i] = z; }
}

// ---------- hist: LDS-privatized bucket histogram ----------
__global__ __launch_bounds__(256) void hist_k(const int* __restrict__ v_ids,
                                              const int* __restrict__ e_ids,
                                              int* __restrict__ gbin, int nnz) {
    __shared__ int hb[NBINS];
    for (int i = threadIdx.x; i < NBINS; i += 256) hb[i] = 0;
    __syncthreads();
    const int nnz4 = nnz >> 2;
    const int b4 = blockIdx.x * (CHUNK_H >> 2);
    #pragma unroll
    for (int u = 0; u < 8; ++u) {
        int i4 = b4 + u * 256 + threadIdx.x;
        if (i4 < nnz4) {
            int4 e = ((const int4*)e_ids)[i4];
            int4 v = ((const int4*)v_ids)[i4];
            #define HA(ee, vv) \
                if ((unsigned)ee < (unsigned)E_N && (unsigned)vv < (unsigned)V_N) { \
                    atomicAdd(&hb[ee >> 8], 1); atomicAdd(&hb[NB_E + (vv >> 8)], 1); }
            HA(e.x, v.x); HA(e.y, v.y); HA(e.z, v.z); HA(e.w, v.w);
            #undef HA
        }
    }
    __syncthreads();
    for (int i = threadIdx.x; i < NBINS; i += 256)
        if (hb[i]) atomicAdd(&gbin[i], hb[i]);
}

// ---------- scanB: exclusive scan over bucket totals -> bases + cursors + off[N] ----------
__global__ __launch_bounds__(1024) void scanB_k(const int* __restrict__ gbin,
                                                int* __restrict__ base_e, int* __restrict__ base_v,
                                                int* __restrict__ curb_e, int* __restrict__ curb_v,
                                                int* __restrict__ off_e, int* __restrict__ off_v) {
    __shared__ int wtot[16];
    const int t = threadIdx.x, lane = t & 63, wid = t >> 6;
    // ---- e buckets ----
    {
        int x = (t < NB_E) ? gbin[t] : 0;
        int incl = x;
        for (int d = 1; d < 64; d <<= 1) { int u = __shfl_up(incl, d); if (lane >= d) incl += u; }
        if (lane == 63) wtot[wid] = incl;
        __syncthreads();
        int carry = 0;
        for (int w = 0; w < wid; ++w) carry += wtot[w];
        int excl = carry + incl - x;
        if (t < NB_E) { base_e[t] = excl; curb_e[t] = excl; }
        if (t == 0) {
            int tot = 0;
            for (int w = 0; w < 16; ++w) tot += wtot[w];
            base_e[NB_E] = tot; off_e[E_N] = tot;
        }
        __syncthreads();
    }
    // ---- v buckets ----
    {
        int x = (t < NB_V) ? gbin[NB_E + t] : 0;
        int incl = x;
        for (int d = 1; d < 64; d <<= 1) { int u = __shfl_up(incl, d); if (lane >= d) incl += u; }
        if (lane == 63) wtot[wid] = incl;
        __syncthreads();
        int carry = 0;
        for (int w = 0; w < wid; ++w) carry += wtot[w];
        int excl = carry + incl - x;
        if (t < NB_V) { base_v[t] = excl; curb_v[t] = excl; }
        if (t == 0) {
            int tot = 0;
            for (int w = 0; w < 16; ++w) tot += wtot[w];
            base_v[NB_V] = tot; off_v[V_N] = tot;
        }
    }
}

// ---------- GEMM body (round-4/6 structure + T14 async-stage split) ----------
// C[m][n] = bf16( post( sum_k A[m][k]*W[k][n] ) + b[n] )
// MODE 0: post=id.  MODE 1: post=*1/max(len,1)  (relu on A happens in seg_e's epilogue)
// Single 32KB LDS: As [128][32] chunk-XOR-swizzled, Wsh [32][128] linear.
template<int MODE>
__device__ __forceinline__ void gemm_body(float* As, float* Wsh, int tile,
                                          const float* __restrict__ A,
                                          const float* __restrict__ W,
                                          const float* __restrict__ bias,
                                          const int* __restrict__ off,
                                          u16* __restrict__ Cout, int M) {
    const int tid = threadIdx.x;
    const int tx = tid & 15;     // n-group
    const int ty = tid >> 4;     // m-group (0..15)
    const int m0 = tile * 128;

    float4 ra[4], rw[4];         // staging registers (A-slice, W-slice)

    auto loadSlice = [&](int kk) {
        #pragma unroll
        for (int u = 0; u < 4; ++u) {
            int f = tid + u * 256;
            int r = f >> 3, c4 = f & 7;
            float4 val = { 0.f, 0.f, 0.f, 0.f };
            if (m0 + r < M)
                val = *(const float4*)(A + (size_t)(m0 + r) * C_N + kk + c4 * 4);
            ra[u] = val;
            int rwr = f >> 5, cw = f & 31;
            rw[u] = *(const float4*)(W + (size_t)(kk + rwr) * C_N + cw * 4);
        }
    };
    auto writeSlice = [&]() {
        #pragma unroll
        for (int u = 0; u < 4; ++u) {
            int f = tid + u * 256;
            int r = f >> 3, c4 = f & 7;
            int sc4 = c4 ^ ((r >> 3) & 7);
            *(float4*)(As + r * 32 + sc4 * 4) = ra[u];
            int rwr = f >> 5, cw = f & 31;
            *(float4*)(Wsh + rwr * 128 + cw * 4) = rw[u];
        }
    };

    float acc[8][8];
    #pragma unroll
    for (int i = 0; i < 8; ++i)
        #pragma unroll
        for (int j = 0; j < 8; ++j) acc[i][j] = 0.f;

    loadSlice(0);
    writeSlice();
    __syncthreads();

    #pragma unroll 1
    for (int kk = 0; kk < 128; kk += 32) {
        if (kk < 96) loadSlice(kk + 32);        // issue next-slice loads (regs)
        #pragma unroll
        for (int k4 = 0; k4 < 32; k4 += 4) {
            float4 a[8];
            #pragma unroll
            for (int i = 0; i < 8; ++i) {
                int row = ty * 8 + i;           // row>>3 == ty
                int sc4 = (k4 >> 2) ^ (ty & 7);
                a[i] = *(const float4*)(As + row * 32 + sc4 * 4);
            }
            #pragma unroll
            for (int dk = 0; dk < 4; ++dk) {
                float4 w0 = *(const float4*)(Wsh + (k4 + dk) * 128 + tx * 4);
                float4 w1 = *(const float4*)(Wsh + (k4 + dk) * 128 + 64 + tx * 4);
                #pragma unroll
                for (int i = 0; i < 8; ++i) {
                    float av = (dk == 0) ? a[i].x : (dk == 1) ? a[i].y : (dk == 2) ? a[i].z : a[i].w;
                    acc[i][0] = fmaf(av, w0.x, acc[i][0]);
                    acc[i][1] = fmaf(av, w0.y, acc[i][1]);
                    acc[i][2] = fmaf(av, w0.z, acc[i][2]);
                    acc[i][3] = fmaf(av, w0.w, acc[i][3]);
                    acc[i][4] = fmaf(av, w1.x, acc[i][4]);
                    acc[i][5] = fmaf(av, w1.y, acc[i][5]);
                    acc[i][6] = fmaf(av, w1.z, acc[i][6]);
                    acc[i][7] = fmaf(av, w1.w, acc[i][7]);
                }
            }
        }
        if (kk < 96) {
            __syncthreads();    // everyone done reading As/Wsh
            writeSlice();       // vmcnt wait lands here, after compute
            __syncthreads();    // slice ready
        }
    }

    float4 bb0 = *(const float4*)(bias + tx * 4);
    float4 bb1 = *(const float4*)(bias + 64 + tx * 4);
    #pragma unroll
    for (int i = 0; i < 8; ++i) {
        int m = m0 + ty * 8 + i;
        if (m >= M) break;
        float inv = 1.f;
        if (MODE) { int len = off[m + 1] - off[m]; inv = 1.f / (float)max(len, 1); }
        float v0, v1, v2, v3, v4, v5, v6, v7;
        if (MODE) {
            v0 = acc[i][0] * inv + bb0.x; v1 = acc[i][1] * inv + bb0.y;
            v2 = acc[i][2] * inv + bb0.z; v3 = acc[i][3] * inv + bb0.w;
            v4 = acc[i][4] * inv + bb1.x; v5 = acc[i][5] * inv + bb1.y;
            v6 = acc[i][6] * inv + bb1.z; v7 = acc[i][7] * inv + bb1.w;
        } else {
            v0 = acc[i][0] + bb0.x; v1 = acc[i][1] + bb0.y;
            v2 = acc[i][2] + bb0.z; v3 = acc[i][3] + bb0.w;
            v4 = acc[i][4] + bb1.x; v5 = acc[i][5] + bb1.y;
            v6 = acc[i][6] + bb1.z; v7 = acc[i][7] + bb1.w;
        }
        u32 p0 = (u32)f2bf(v0) | ((u32)f2bf(v1) << 16);
        u32 p1 = (u32)f2bf(v2) | ((u32)f2bf(v3) << 16);
        u32 p2 = (u32)f2bf(v4) | ((u32)f2bf(v5) << 16);
        u32 p3 = (u32)f2bf(v6) | ((u32)f2bf(v7) << 16);
        u32* dst = (u32*)(Cout + (size_t)m * C_N);
        uint2 q0 = { p0, p1 }, q1 = { p2, p3 };
        *(uint2*)(dst + tx * 2) = q0;
        *(uint2*)(dst + 32 + tx * 2) = q1;
    }
}

// ---------- fused: blocks [0,G1T) = gemm1 tiles; blocks [G1T, G1T+NCHA) = passA chunks ----------
// passA partitions pairs into bucket-contiguous arrays with coalesced writes.
// pair pack: e-dir (elow 8b << 17) | v (17b);  v-dir (vlow 8b << 16) | e (16b)
// 256 threads, CHUNK_A=4096, LDS overlay fits in gemm's 32KB union.
__global__ __launch_bounds__(256) void g1passA_k(const float* __restrict__ X,
                                                 const float* __restrict__ W,
                                                 const float* __restrict__ bias,
                                                 u16* __restrict__ Xp,
                                                 const int* __restrict__ v_ids,
                                                 const int* __restrict__ e_ids,
                                                 int* __restrict__ curb_e, int* __restrict__ curb_v,
                                                 u32* __restrict__ pairs_e, u32* __restrict__ pairs_v,
                                                 int nnz) {
    __shared__ __align__(16) float sm[2][4096];   // 32KB
    if ((int)blockIdx.x < G1T) {
        gemm_body<0>(sm[0], sm[1], blockIdx.x, X, W, bias, nullptr, Xp, V_N);
        return;
    }
    // ---- passA on a 4096-entry chunk ----
    const int bid = blockIdx.x - G1T;
    u32* stage  = (u32*)&sm[0][0];                 // [4096]  16KB
    int* cnt    = (int*)&sm[0][0] + 4096;          // [392]
    int* runoff = (int*)&sm[0][0] + 4496;          // [392+1]
    int* delta  = (int*)&sm[0][0] + 4896;          // [392]
    int* cnt2   = (int*)&sm[0][0] + 5296;          // [392]
    int* wtot   = (int*)&sm[0][0] + 5696;          // [4]
    const int t = threadIdx.x, lane = t & 63, wid = t >> 6;
    const int nnz4 = nnz >> 2;
    const int b4 = bid * (CHUNK_A >> 2);           // 1024 int4s per chunk

    for (int dir = 0; dir < 2; ++dir) {
        const int nb = dir ? NB_V : NB_E;
        for (int i = t; i < nb; i += 256) { cnt[i] = 0; cnt2[i] = 0; }
        __syncthreads();
        // count (re-read ids from global; L2/L3-resident)
        #pragma unroll
        for (int u = 0; u < 4; ++u) {
            int i4 = b4 + u * 256 + t;
            if (i4 < nnz4) {
                int4 e = ((const int4*)e_ids)[i4];
                int4 v = ((const int4*)v_ids)[i4];
                #define PC(ee, vv) \
                    if ((unsigned)ee < (unsigned)E_N && (unsigned)vv < (unsigned)V_N) { \
                        int k_ = dir ? vv : ee; atomicAdd(&cnt[k_ >> 8], 1); }
                PC(e.x, v.x); PC(e.y, v.y); PC(e.z, v.z); PC(e.w, v.w);
                #undef PC
            }
        }
        __syncthreads();
        // exclusive scan over cnt[0..nb) with 256 threads (rounds of 256)
        int carryAll = 0;
        for (int base = 0; base < nb; base += 256) {
            int x = (base + t < nb) ? cnt[base + t] : 0;
            int incl = x;
            for (int d = 1; d < 64; d <<= 1) { int u = __shfl_up(incl, d); if (lane >= d) incl += u; }
            if (lane == 63) wtot[wid] = incl;
            __syncthreads();
            int wc = 0;
            for (int w = 0; w < wid; ++w) wc += wtot[w];
            if (base + t < nb) runoff[base + t] = carryAll + wc + incl - x;
            carryAll += wtot[0] + wtot[1] + wtot[2] + wtot[3];
            __syncthreads();
        }
        if (t == 0) runoff[nb] = carryAll;
        __syncthreads();
        const int total = runoff[nb];
        // reserve global runs (one atomic per nonempty bucket)
        for (int i = t; i < nb; i += 256)
            if (cnt[i] > 0) {
                int r = atomicAdd((dir ? curb_v : curb_e) + i, cnt[i]);
                delta[i] = r - runoff[i];
            }
        __syncthreads();
        // scatter into LDS staging grouped by bucket (second global read pass)
        #pragma unroll
        for (int u = 0; u < 4; ++u) {
            int i4 = b4 + u * 256 + t;
            if (i4 < nnz4) {
                int4 e = ((const int4*)e_ids)[i4];
                int4 v = ((const int4*)v_ids)[i4];
                #define PS(ee, vv) \
                    if ((unsigned)ee < (unsigned)E_N && (unsigned)vv < (unsigned)V_N) { \
                        int k_ = dir ? vv : ee; int b_ = k_ >> 8; \
                        u32 pk_ = dir ? (((u32)(k_ & 255) << 16) | (u32)ee) \
                                      : (((u32)(k_ & 255) << 17) | (u32)vv); \
                        int idx_ = runoff[b_] + atomicAdd(&cnt2[b_], 1); \
                        stage[idx_] = pk_; }
                PS(e.x, v.x); PS(e.y, v.y); PS(e.z, v.z); PS(e.w, v.w);
                #undef PS
            }
        }
        __syncthreads();
        // coalesced flush (binary-search bucket of each staged slot)
        u32* pairs = dir ? pairs_v : pairs_e;
        for (int i = t; i < total; i += 256) {
            int lo = 0, hi = nb;
            while (hi - lo > 1) { int mid = (lo + hi) >> 1; if (runoff[mid] <= i) lo = mid; else hi = mid; }
            pairs[i + delta[lo]] = stage[i];
        }
        __syncthreads();
    }
}

__global__ __launch_bounds__(256) void gemm2_k(const float* __restrict__ A,
                                               const float* __restrict__ W,
                                               const float* __restrict__ bias,
                                               const int* __restrict__ off,
                                               u16* __restrict__ Cout, int M) {
    __shared__ __align__(16) float sm[2][4096];   // 32KB
    gemm_body<1>(sm[0], sm[1], blockIdx.x, A, W, bias, off, Cout, M);
}

// ---------- passB: per-bucket CSR finalize, LDS-staged, coalesced in/out ----------
__global__ __launch_bounds__(256) void passB_k(const u32* __restrict__ pairs_e,
                                               const u32* __restrict__ pairs_v,
                                               const int* __restrict__ base_e,
                                               const int* __restrict__ base_v,
                                               int* __restrict__ off_e, int* __restrict__ off_v,
                                               int* __restrict__ se_src, int* __restrict__ sv_src) {
    __shared__ int cntk[256], curk[256];
    __shared__ u32 buf[CAP_B];
    __shared__ int wtot[4];
    int b = blockIdx.x;
    const u32* pairs; const int* base; int* off; int* outv; int keyN, shift; u32 mask;
    if (b < NB_E) { pairs = pairs_e; base = base_e; off = off_e; outv = se_src; keyN = E_N; shift = 17; mask = 0x1FFFFu; }
    else { b -= NB_E; pairs = pairs_v; base = base_v; off = off_v; outv = sv_src; keyN = V_N; shift = 16; mask = 0xFFFFu; }
    const int lo = base[b], hi = base[b + 1], cnt = hi - lo, k0 = b << 8;
    const int t = threadIdx.x, lane = t & 63, wid = t >> 6;
    cntk[t] = 0;
    __syncthreads();
    for (int i = t; i < cnt; i += 256) { u32 p = pairs[lo + i]; atomicAdd(&cntk[p >> shift], 1); }
    __syncthreads();
    int x = cntk[t];
    int incl = x;
    for (int d = 1; d < 64; d <<= 1) { int u = __shfl_up(incl, d); if (lane >= d) incl += u; }
    if (lane == 63) wtot[wid] = incl;
    __syncthreads();
    int carry = 0;
    for (int w = 0; w < wid; ++w) carry += wtot[w];
    int excl = carry + incl - x;
    if (k0 + t < keyN) off[k0 + t] = lo + excl;
    curk[t] = excl;
    __syncthreads();
    if (cnt <= CAP_B) {
        for (int i = t; i < cnt; i += 256) {
            u32 p = pairs[lo + i];
            int pos = atomicAdd(&curk[p >> shift], 1);
            buf[pos] = p & mask;
        }
        __syncthreads();
        for (int i = t; i < cnt; i += 256) outv[lo + i] = (int)buf[i];
    } else {
        // statistically unreachable fallback (keeps correctness unconditional)
        for (int i = t; i < cnt; i += 256) {
            u32 p = pairs[lo + i];
            int pos = atomicAdd(&curk[p >> shift], 1);
            outv[lo + pos] = (int)(p & mask);
        }
    }
}

// ---------- seg: out[seg][c] = post( sum over segment of F[src][c] )  (1 wave per segment) ----------
// MODE 0 (seg_e): post = relu(sum)          [f32 out; /len folded into gemm2 epilogue]
// MODE 1 (seg_v): post = relu(sum/max(len,1))
// Lane layout: q = lane>>4 picks row within a quad; c = lane&15 covers channels 8c..8c+7 (uint4).
// One 64-lane uint4 load gathers FOUR rows; 4-load unroll keeps 16 rows in flight.
template<int MODE>
__global__ __launch_bounds__(256) void seg16_k(const u16* __restrict__ F,
                                               const int* __restrict__ off,
                                               const int* __restrict__ srcs,
                                               float* __restrict__ out, int N) {
    int seg = blockIdx.x * 4 + (threadIdx.x >> 6);
    if (seg >= N) return;
    const int lane = threadIdx.x & 63;
    const int q = lane >> 4;
    const int c = lane & 15;
    int j0 = off[seg], j1 = off[seg + 1];
    float a0 = 0.f, a1 = 0.f, a2 = 0.f, a3 = 0.f, a4 = 0.f, a5 = 0.f, a6 = 0.f, a7 = 0.f;
    #define ACC8(u) { float l_, h_; \
        unpack2(u.x, l_, h_); a0 += l_; a1 += h_; \
        unpack2(u.y, l_, h_); a2 += l_; a3 += h_; \
        unpack2(u.z, l_, h_); a4 += l_; a5 += h_; \
        unpack2(u.w, l_, h_); a6 += l_; a7 += h_; }
    int j = j0;
    for (; j + 16 <= j1; j += 16) {
        int s0 = srcs[j + q];
        int s1 = srcs[j + 4 + q];
        int s2 = srcs[j + 8 + q];
        int s3 = srcs[j + 12 + q];
        uint4 u0 = ((const uint4*)(F + (size_t)s0 * C_N))[c];
        uint4 u1 = ((const uint4*)(F + (size_t)s1 * C_N))[c];
        uint4 u2 = ((const uint4*)(F + (size_t)s2 * C_N))[c];
        uint4 u3 = ((const uint4*)(F + (size_t)s3 * C_N))[c];
        ACC8(u0); ACC8(u1); ACC8(u2); ACC8(u3);
    }
    for (; j + 4 <= j1; j += 4) {
        int s0 = srcs[j + q];
        uint4 u0 = ((const uint4*)(F + (size_t)s0 * C_N))[c];
        ACC8(u0);
    }
    if (j + q < j1) {
        int s0 = srcs[j + q];
        uint4 u0 = ((const uint4*)(F + (size_t)s0 * C_N))[c];
        ACC8(u0);
    }
    #undef ACC8
    a0 += __shfl_xor(a0, 16); a0 += __shfl_xor(a0, 32);
    a1 += __shfl_xor(a1, 16); a1 += __shfl_xor(a1, 32);
    a2 += __shfl_xor(a2, 16); a2 += __shfl_xor(a2, 32);
    a3 += __shfl_xor(a3, 16); a3 += __shfl_xor(a3, 32);
    a4 += __shfl_xor(a4, 16); a4 += __shfl_xor(a4, 32);
    a5 += __shfl_xor(a5, 16); a5 += __shfl_xor(a5, 32);
    a6 += __shfl_xor(a6, 16); a6 += __shfl_xor(a6, 32);
    a7 += __shfl_xor(a7, 16); a7 += __shfl_xor(a7, 32);
    if (q == 0) {
        float inv = MODE ? (1.0f / (float)max(j1 - j0, 1)) : 1.0f;
        float4 w0, w1;
        w0.x = fmaxf(a0 * inv, 0.f); w0.y = fmaxf(a1 * inv, 0.f);
        w0.z = fmaxf(a2 * inv, 0.f); w0.w = fmaxf(a3 * inv, 0.f);
        w1.x = fmaxf(a4 * inv, 0.f); w1.y = fmaxf(a5 * inv, 0.f);
        w1.z = fmaxf(a6 * inv, 0.f); w1.w = fmaxf(a7 * inv, 0.f);
        float4* o = (float4*)(out + (size_t)seg * C_N + c * 8);
        o[0] = w0; o[1] = w1;
    }
}

// ---------- launch ----------
extern "C" void kernel_launch(void* const* d_in, const int* in_sizes, int n_in,
                              void* d_out, int out_size, void* d_ws, size_t ws_size,
                              hipStream_t stream) {
    const float* X     = (const float*)d_in[0];
    const float* W_v2e = (const float*)d_in[1];
    const float* b_v2e = (const float*)d_in[2];
    const float* W_e2v = (const float*)d_in[3];
    const float* b_e2v = (const float*)d_in[4];
    const int*   v_ids = (const int*)d_in[5];
    const int*   e_ids = (const int*)d_in[6];
    float* out = (float*)d_out;   // f32 [V][128]

    bool sizesOK = (n_in == 7) && (out_size == 12800000)
        && in_sizes[0] == 12800000 && in_sizes[1] == 16384 && in_sizes[2] == 128
        && in_sizes[3] == 16384 && in_sizes[4] == 128
        && in_sizes[5] == 1600000 && in_sizes[6] == 1600000;
    if (!sizesOK) { flagf_k<<<1, 64, 0, stream>>>(out, 1.0e6f); return; }
    if (ws_size < 28000000) { flagf_k<<<1, 64, 0, stream>>>(out, 2.0e6f); return; }
    const int nnz = in_sizes[5];

    // d_out (51.2 MB) doubles as scratch:
    //   Xp bf16 [V][128] @ 0 (25.6M)               -- written by g1passA (gemm1), read by seg_e
    //   pairs_e u32[nnz] @ 25.6M, pairs_v @ 32M    -- written by g1passA (passA), dead after passB
    //   Ysum f32 [E][128] @ 25.6M (25.6M)          -- written by seg_e (over dead pairs)
    //   out f32 [V][128] @ 0                       -- final write by seg_v
    u16*   Xp      = (u16*)d_out;
    u32*   pairs_e = (u32*)((char*)d_out + 25600000);
    u32*   pairs_v = pairs_e + nnz;
    float* Ysum    = (float*)((char*)d_out + 25600000);

    // ws layout (bytes):
    char* ws = (char*)d_ws;
    u16* Yp     = (u16*)(ws + 0);                   // bf16 [E][128] (12.8M)
    int* se_src = (int*)(ws + 12800000);            // int[nnz]
    int* sv_src = (int*)(ws + 19200000);            // int[nnz]
    int* gbin   = (int*)(ws + 25600000);            // 587 (+pad to 640)
    int* base_e = (int*)(ws + 25602560);            // 197
    int* base_v = (int*)(ws + 25603584);            // 392
    int* curb_e = (int*)(ws + 25605632);            // 196
    int* curb_v = (int*)(ws + 25606656);            // 391
    int* off_e  = (int*)(ws + 25608704);            // 50001
    int* off_v  = (int*)(ws + 25808768);            // 100001  (ends ~26.2M)

    const int NCHH = (nnz + CHUNK_H - 1) / CHUNK_H; // 196 hist chunks
    const int NCHA = (nnz + CHUNK_A - 1) / CHUNK_A; // 391 passA chunks

    zero_i4<<<1, 256, 0, stream>>>((int4*)gbin, 152);   // 608 ints >= 587, within pad
    hist_k<<<NCHH, 256, 0, stream>>>(v_ids, e_ids, gbin, nnz);
    scanB_k<<<1, 1024, 0, stream>>>(gbin, base_e, base_v, curb_e, curb_v, off_e, off_v);
    // gemm1 (782 tiles) runs concurrently with passA (391 chunks)
    g1passA_k<<<G1T + NCHA, 256, 0, stream>>>(X, W_v2e, b_v2e, Xp, v_ids, e_ids,
                                              curb_e, curb_v, pairs_e, pairs_v, nnz);
    passB_k<<<NBINS, 256, 0, stream>>>(pairs_e, pairs_v, base_e, base_v, off_e, off_v, se_src, sv_src);

    seg16_k<0><<<(E_N + 3) / 4, 256, 0, stream>>>(Xp, off_e, se_src, Ysum, E_N);
    gemm2_k<<<G2T, 256, 0, stream>>>(Ysum, W_e2v, b_e2v, off_e, Yp, E_N);
    seg16_k<1><<<(V_N + 3) / 4, 256, 0, stream>>>(Yp, off_v, sv_src, out, V_N);

    (void)ws_size;
}